// Round 6
// baseline (320.156 us; speedup 1.0000x reference)
//
#include <hip/hip_runtime.h>
#include <hip/hip_bf16.h>

// GCN: h = lrelu(bn(gcn(x,W1)))  ; 2x h = lrelu(bn(gcn(h,Wi)) + h) ; lrelu(h@L1+b) ; h@L2+b
// R15: per-group gather (R12, 64 lanes each walking own edge list -> ~32 rows in
// flight/wave, fetch 2.5 TB/s measured) + R14 LDS-coalesced hwout epilogue (write amp
// fixed). Kernel merges: wswz folded into bin (one dispatch), gemm1 folded into scatter
// (same 64-node block ownership, dis via LDS). 6 dispatches total.

constexpr int   NN    = 50000;
constexpr int   EE    = 800000;
constexpr int   CH    = 128;
constexpr int   SLOTS = 64;               // word0 = counter, slots 1..63 = edges
constexpr int   NBUK  = 782;              // buckets of 64 nodes (dst >> 6)
constexpr int   RCAP  = 2048;             // bin region capacity per bucket
constexpr int   EPB   = 2048;             // edges per bin block
constexpr int   NB_BIN = (EE + EPB - 1) / EPB;       // 391
constexpr int   NB_WZ  = (73728 + 384 + 255) / 256;  // 290
constexpr float EPS   = 1e-5f;

typedef __attribute__((ext_vector_type(8))) short bf16x8;
typedef __attribute__((ext_vector_type(4))) float f32x4;
typedef unsigned long long u64;
typedef unsigned short u16;

__device__ inline u16 f2bf_rne(float f) {
  unsigned u = __float_as_uint(f);
  unsigned r = u + 0x7fffu + ((u >> 16) & 1u);
  return (u16)(r >> 16);
}
__device__ inline float bf2f(unsigned h16) {          // low 16 bits -> float
  return __uint_as_float(h16 << 16);
}

// ---------------- pass 1: bin edges by dst bucket, + weight swizzle ----------------

__global__ __launch_bounds__(256) void binw_kernel(
    const int* __restrict__ ei, const float* __restrict__ ew,
    unsigned* __restrict__ gcur, u64* __restrict__ bins,
    const float* __restrict__ w1, const float* __restrict__ bn1_g, const float* __restrict__ bn1_v,
    const float* __restrict__ conv_ws, const float* __restrict__ bns_g, const float* __restrict__ bns_v,
    const float* __restrict__ lin1_w, const float* __restrict__ lin2_w,
    const float* __restrict__ b1, const float* __restrict__ bn1_b, const float* __restrict__ bn1_m,
    const float* __restrict__ conv_bs, const float* __restrict__ bns_b, const float* __restrict__ bns_m,
    u16* __restrict__ w1h, u16* __restrict__ w1l,
    u16* __restrict__ c0h, u16* __restrict__ c0l,
    u16* __restrict__ c1h, u16* __restrict__ c1l,
    u16* __restrict__ l1h, u16* __restrict__ l1l,
    u16* __restrict__ l2h, u16* __restrict__ l2l,
    float* __restrict__ beff)
{
  const int tid = threadIdx.x;
  if (blockIdx.x >= NB_BIN) {
    // ---- wswz role ----
    int idx = (blockIdx.x - NB_BIN) * 256 + tid;
    if (idx >= 73728) {
      int r = idx - 73728;
      if (r >= 384) return;
      int l = r >> 7, c = r & 127;
      float bc, gg, bb, mm, vv;
      if (l == 0) { bc = b1[c]; gg = bn1_g[c]; bb = bn1_b[c]; mm = bn1_m[c]; vv = bn1_v[c]; }
      else {
        int o = (l - 1) * 128 + c;
        bc = conv_bs[o]; gg = bns_g[o]; bb = bns_b[o]; mm = bns_m[o]; vv = bns_v[o];
      }
      beff[r] = (bc - mm) * gg * rsqrtf(vv + EPS) + bb;
      return;
    }
    const float* W; const float* g = nullptr; const float* v = nullptr;
    u16 *hi, *lo; int CO = 128; int local;
    if      (idx < 16384) { W = w1;              g = bn1_g;     v = bn1_v;     hi = w1h; lo = w1l; local = idx; }
    else if (idx < 32768) { W = conv_ws;         g = bns_g;     v = bns_v;     hi = c0h; lo = c0l; local = idx - 16384; }
    else if (idx < 49152) { W = conv_ws + 16384; g = bns_g+128; v = bns_v+128; hi = c1h; lo = c1l; local = idx - 32768; }
    else if (idx < 65536) { W = lin1_w;                                        hi = l1h; lo = l1l; local = idx - 49152; }
    else                  { W = lin2_w;                                        hi = l2h; lo = l2l; local = idx - 65536; CO = 64; }
    int k = local / CO, n = local % CO;
    float w = W[local];
    if (g) w *= g[n] * rsqrtf(v[n] + EPS);
    int NCT = CO / 16;
    int kchunk = k >> 5, kin = k & 31, quad = kin >> 3, j = kin & 7;
    int ct = n >> 4, l = (quad << 4) | (n & 15);
    size_t pos = ((size_t)(kchunk * NCT + ct) * 64 + l) * 8 + j;
    u16 h = f2bf_rne(w);
    hi[pos] = h;
    lo[pos] = f2bf_rne(w - bf2f(h));
    return;
  }
  // ---- bin role ----
  __shared__ unsigned cnt[NBUK];
  __shared__ unsigned base[NBUK];
  for (int b = tid; b < NBUK; b += 256) cnt[b] = 0;
  __syncthreads();
  const int e0 = blockIdx.x * EPB;
  unsigned pk[8]; u16 bkt[8]; u16 rnk[8]; unsigned char dl[8];
  #pragma unroll
  for (int i = 0; i < 8; i++) {
    int e = e0 + i * 256 + tid;
    if (e < EE) {
      int s = ei[e], d = ei[EE + e];
      float w = ew[e];
      bkt[i] = (u16)(d >> 6);
      dl[i]  = (unsigned char)(d & 63);
      pk[i]  = ((unsigned)f2bf_rne(w) << 16) | (unsigned)s;
      rnk[i] = (u16)atomicAdd(&cnt[bkt[i]], 1u);
    } else bkt[i] = 0xffffu;
  }
  __syncthreads();
  for (int b = tid; b < NBUK; b += 256) {
    unsigned c = cnt[b];
    base[b] = c ? atomicAdd(&gcur[b * 16], c) : 0u;
  }
  __syncthreads();
  #pragma unroll
  for (int i = 0; i < 8; i++) {
    if (bkt[i] == 0xffffu) continue;
    unsigned pos = base[bkt[i]] + rnk[i];
    if (pos < RCAP)
      bins[(size_t)bkt[i] * RCAP + pos] = ((u64)dl[i] << 32) | pk[i];
  }
}

// ---------------- pass 2: scatter bucket -> ELL, then layer-1 GEMM for same rows ----

__global__ __launch_bounds__(256) void scatgemm_kernel(
    const unsigned* __restrict__ gcur, const u64* __restrict__ bins,
    unsigned* __restrict__ ell, float* __restrict__ dis,
    const float* __restrict__ Ain,
    const u16* __restrict__ Whi, const u16* __restrict__ Wlo,
    u16* __restrict__ Cout)
{
  __shared__ unsigned rank[64];
  __shared__ float    wsum[64];
  __shared__ float    disl[64];
  __shared__ float    lds[64][CH + 4];
  const int b   = blockIdx.x;
  const int tid = threadIdx.x;

  // ---- phase A: scatter ----
  if (tid < 64) { rank[tid] = 1u; wsum[tid] = 0.f; }
  __syncthreads();
  unsigned cnt = gcur[b * 16];
  if (cnt > RCAP) cnt = RCAP;
  const u64* src = bins + (size_t)b * RCAP;
  for (unsigned i = tid; i < cnt; i += 256) {
    u64 v = src[i];
    unsigned pk = (unsigned)v;
    unsigned dl = (unsigned)(v >> 32);
    unsigned r = atomicAdd(&rank[dl], 1u);
    if (r < SLOTS)
      ell[((size_t)(b * 64 + dl)) * SLOTS + r] = pk;
    atomicAdd(&wsum[dl], bf2f(pk >> 16));
  }
  __syncthreads();
  if (tid < 64) {
    int node = b * 64 + tid;
    float d = rsqrtf(1.0f + wsum[tid]);
    disl[tid] = d;
    if (node < NN) {
      unsigned c = rank[tid];
      if (c > SLOTS) c = SLOTS;
      ell[(size_t)node * SLOTS] = c;
      dis[node] = d;
    }
  }
  __syncthreads();

  // ---- phase B: gemm1 for rows [b*64, b*64+64) ----
  const int wave = tid >> 6;
  const int lane = tid & 63;
  const int quad = lane >> 4;
  const int mrow = lane & 15;
  const int row0 = b * 64;

  int arow = row0 + wave * 16 + mrow;
  if (arow >= NN) arow = NN - 1;

  bf16x8 ahi[4], alo[4];
  const float* Ar = Ain + (size_t)arow * CH;
  #pragma unroll
  for (int c = 0; c < 4; c++) {
    int off = c * 32 + quad * 8;
    float4 f0 = *(const float4*)(Ar + off);
    float4 f1 = *(const float4*)(Ar + off + 4);
    float f[8] = {f0.x, f0.y, f0.z, f0.w, f1.x, f1.y, f1.z, f1.w};
    #pragma unroll
    for (int j = 0; j < 8; j++) {
      u16 h = f2bf_rne(f[j]);
      ahi[c][j] = (short)h;
      alo[c][j] = (short)f2bf_rne(f[j] - bf2f(h));
    }
  }

  f32x4 acc[8];
  #pragma unroll
  for (int t = 0; t < 8; t++) acc[t] = (f32x4){0.f, 0.f, 0.f, 0.f};
  #pragma unroll
  for (int c = 0; c < 4; c++) {
    #pragma unroll
    for (int t = 0; t < 8; t++) {
      size_t base = ((size_t)(c * 8 + t) * 64 + lane) * 8;
      bf16x8 bh = *(const bf16x8*)(Whi + base);
      bf16x8 bl = *(const bf16x8*)(Wlo + base);
      acc[t] = __builtin_amdgcn_mfma_f32_16x16x32_bf16(ahi[c], bh, acc[t], 0, 0, 0);
      acc[t] = __builtin_amdgcn_mfma_f32_16x16x32_bf16(alo[c], bh, acc[t], 0, 0, 0);
      acc[t] = __builtin_amdgcn_mfma_f32_16x16x32_bf16(ahi[c], bl, acc[t], 0, 0, 0);
    }
  }

  #pragma unroll
  for (int t = 0; t < 8; t++)
    #pragma unroll
    for (int r = 0; r < 4; r++)
      lds[wave * 16 + quad * 4 + r][t * 16 + mrow] = acc[t][r];
  __syncthreads();

  #pragma unroll
  for (int i = tid; i < 64 * CH / 4; i += 256) {
    int row = (i * 4) / CH;
    int col = (i * 4) % CH;
    int grow = row0 + row;
    if (grow >= NN) continue;
    float rs = disl[row];
    const float* lp = &lds[row][col];
    u16* cp = (u16*)Cout + (size_t)grow * CH + col;
    unsigned p0 = ((unsigned)f2bf_rne(lp[1] * rs) << 16) | f2bf_rne(lp[0] * rs);
    unsigned p1 = ((unsigned)f2bf_rne(lp[3] * rs) << 16) | f2bf_rne(lp[2] * rs);
    *(uint2*)cp = make_uint2(p0, p1);
  }
}

// ---------------- per-group gather (shared by fuse kernels) ----------------
// Each 16-lane group owns one node. Lane (grp,sub) accumulates channels sub*8..+7
// of node nbase+grp over that node's edges, 8 edges per static-unrolled step.
// No cross-lane reduction needed; hout row write is fully coalesced (16 lanes x 16B).
template<bool RES, bool WH>
__device__ __forceinline__ void gather4_grp(
    const u16* __restrict__ hwin, const unsigned* __restrict__ ell,
    const float* __restrict__ dis, const float* __restrict__ beff,
    const u16* __restrict__ res, u16* __restrict__ hout,
    unsigned* __restrict__ hsbase,           // &hs[wave*4][0], pitch 68 uints
    int nbase, int lane, int sub, int grp)
{
  const int node = nbase + grp;              // grid is exact: node < NN always
  const size_t ebase = (size_t)node * SLOTS + sub;
  unsigned w0 = ell[ebase];
  unsigned w1 = ell[ebase + 16];
  unsigned w2 = ell[ebase + 32];
  unsigned w3 = ell[ebase + 48];

  int cme = __shfl((int)w0, grp << 4); if (cme > SLOTS) cme = SLOTS;
  int c0 = __shfl((int)w0, 0),  c1 = __shfl((int)w0, 16);
  int c2 = __shfl((int)w0, 32), c3 = __shfl((int)w0, 48);
  int cmax = max(max(c0, c1), max(c2, c3)); if (cmax > SLOTS) cmax = SLOTS;

  float a[8] = {0.f, 0.f, 0.f, 0.f, 0.f, 0.f, 0.f, 0.f};
  const u16* hrow = hwin + sub * 8;

  for (int j = 0; j < cmax; j += 8) {
    uint4 hQ[8]; float wQ[8];
    #pragma unroll
    for (int u = 0; u < 8; u++) {
      int jj = j + u;
      int k = jj >> 4;
      unsigned wsel = k == 0 ? w0 : (k == 1 ? w1 : (k == 2 ? w2 : w3));
      unsigned e = (unsigned)__shfl((int)wsel, (grp << 4) | (jj & 15));
      float wv = (jj == 0) ? 1.0f : bf2f(e >> 16);
      unsigned s = (jj == 0) ? (unsigned)node : (e & 0xffffu);
      if (jj >= cme) { wv = 0.f; s = (unsigned)node; }
      wQ[u] = wv;
      hQ[u] = *(const uint4*)(hrow + (size_t)s * CH);
    }
    #pragma unroll
    for (int u = 0; u < 8; u++) {
      float w = wQ[u];
      a[0] = fmaf(w, bf2f(hQ[u].x & 0xffffu), a[0]); a[1] = fmaf(w, bf2f(hQ[u].x >> 16), a[1]);
      a[2] = fmaf(w, bf2f(hQ[u].y & 0xffffu), a[2]); a[3] = fmaf(w, bf2f(hQ[u].y >> 16), a[3]);
      a[4] = fmaf(w, bf2f(hQ[u].z & 0xffffu), a[4]); a[5] = fmaf(w, bf2f(hQ[u].z >> 16), a[5]);
      a[6] = fmaf(w, bf2f(hQ[u].w & 0xffffu), a[6]); a[7] = fmaf(w, bf2f(hQ[u].w >> 16), a[7]);
    }
  }

  // epilogue: all 64 lanes active; lane (grp,sub) finalizes its channels
  float disd = dis[node];
  int c = sub * 8;
  float4 be0 = *(const float4*)(beff + c);
  float4 be1 = *(const float4*)(beff + c + 4);
  float y[8];
  y[0] = a[0] * disd + be0.x; y[1] = a[1] * disd + be0.y;
  y[2] = a[2] * disd + be0.z; y[3] = a[3] * disd + be0.w;
  y[4] = a[4] * disd + be1.x; y[5] = a[5] * disd + be1.y;
  y[6] = a[6] * disd + be1.z; y[7] = a[7] * disd + be1.w;
  if constexpr (RES) {
    uint4 rr = *(const uint4*)(res + (size_t)node * CH + c);
    y[0] += bf2f(rr.x & 0xffffu); y[1] += bf2f(rr.x >> 16);
    y[2] += bf2f(rr.y & 0xffffu); y[3] += bf2f(rr.y >> 16);
    y[4] += bf2f(rr.z & 0xffffu); y[5] += bf2f(rr.z >> 16);
    y[6] += bf2f(rr.w & 0xffffu); y[7] += bf2f(rr.w >> 16);
  }
  #pragma unroll
  for (int k = 0; k < 8; k++) y[k] = y[k] > 0.f ? y[k] : 0.01f * y[k];
  uint4 o;
  o.x = ((unsigned)f2bf_rne(y[1]) << 16) | f2bf_rne(y[0]);
  o.y = ((unsigned)f2bf_rne(y[3]) << 16) | f2bf_rne(y[2]);
  o.z = ((unsigned)f2bf_rne(y[5]) << 16) | f2bf_rne(y[4]);
  o.w = ((unsigned)f2bf_rne(y[7]) << 16) | f2bf_rne(y[6]);
  if constexpr (WH)
    *(uint4*)(hout + (size_t)node * CH + c) = o;
  *(uint4*)&hsbase[grp * 68 + sub * 4] = o;
}

// ---------------- fused agg + GEMM (layers 2/3), 16 nodes/block ----------------
// hwout epilogue goes through LDS so rows are written as full coalesced uint4 lines.
template<bool RES>
__global__ __launch_bounds__(256, 6) void fuse_kernel(
    const u16* __restrict__ hwin,
    const unsigned* __restrict__ ell, const float* __restrict__ dis,
    const float* __restrict__ beff, const u16* __restrict__ res,
    const u16* __restrict__ Whi, const u16* __restrict__ Wlo,
    u16* __restrict__ hout, u16* __restrict__ hwout)
{
  __shared__ unsigned hs[16][68];          // packed bf16 pairs, 2 ch per uint
  const int tid  = threadIdx.x;
  const int wave = tid >> 6;
  const int lane = tid & 63;
  const int sub  = lane & 15;
  const int grp  = lane >> 4;
  const int row0 = blockIdx.x * 16;

  gather4_grp<RES, true>(hwin, ell, dis, beff, res, hout,
                         &hs[wave * 4][0], row0 + wave * 4, lane, sub, grp);
  __syncthreads();   // rows are cross-wave in phase 2

  // ---- phase 2: GEMM, wave computes 16 rows x cols [wave*32, wave*32+32) ----
  bf16x8 af[4];
  #pragma unroll
  for (int c = 0; c < 4; c++)
    af[c] = *(const bf16x8*)&hs[sub][c * 16 + grp * 4];
  __syncthreads();   // all af reads complete before hs is overwritten below

  f32x4 acc[2];
  #pragma unroll
  for (int t = 0; t < 2; t++) acc[t] = (f32x4){0.f, 0.f, 0.f, 0.f};
  #pragma unroll
  for (int c = 0; c < 4; c++) {
    #pragma unroll
    for (int t = 0; t < 2; t++) {
      size_t base = ((size_t)(c * 8 + wave * 2 + t) * 64 + lane) * 8;
      bf16x8 bh = *(const bf16x8*)(Whi + base);
      bf16x8 bl = *(const bf16x8*)(Wlo + base);
      acc[t] = __builtin_amdgcn_mfma_f32_16x16x32_bf16(af[c], bh, acc[t], 0, 0, 0);
      acc[t] = __builtin_amdgcn_mfma_f32_16x16x32_bf16(af[c], bl, acc[t], 0, 0, 0);
    }
  }

  // scale + pack into LDS (u16 view, pitch 136), then coalesced uint4 row writes
  u16* hs16 = (u16*)&hs[0][0];
  #pragma unroll
  for (int r = 0; r < 4; r++) {
    int row = grp * 4 + r;                  // C/D: row = grp*4+r
    float rs = dis[row0 + row];
    #pragma unroll
    for (int t = 0; t < 2; t++)
      hs16[row * 136 + wave * 32 + t * 16 + sub] = f2bf_rne(acc[t][r] * rs);
  }
  __syncthreads();
  {
    int row   = tid >> 4;                   // 0..15
    int chunk = tid & 15;                   // 16B chunks
    uint4 o = *(const uint4*)(hs16 + row * 136 + chunk * 8);
    *(uint4*)(hwout + (size_t)(row0 + row) * CH + chunk * 8) = o;
  }
}

// ---------------- fused agg3 + lin1 + lin2: out = lrelu(h3@L1+b1)@L2+b2 ----------
__global__ __launch_bounds__(256, 6) void fuse_last_kernel(
    const u16* __restrict__ hwin,
    const unsigned* __restrict__ ell, const float* __restrict__ dis,
    const float* __restrict__ beff, const u16* __restrict__ res,
    const u16* __restrict__ l1h, const u16* __restrict__ l1l,
    const float* __restrict__ b1,
    const u16* __restrict__ l2h, const u16* __restrict__ l2l,
    const float* __restrict__ b2, float* __restrict__ out)
{
  __shared__ unsigned hs[16][68];          // bf16 h-tile
  __shared__ float    fs[16][132];         // fp32 lin1 output tile
  const int tid  = threadIdx.x;
  const int wave = tid >> 6;
  const int lane = tid & 63;
  const int sub  = lane & 15;
  const int grp  = lane >> 4;
  const int row0 = blockIdx.x * 16;

  gather4_grp<true, false>(hwin, ell, dis, beff, res, nullptr,
                           &hs[wave * 4][0], row0 + wave * 4, lane, sub, grp);
  __syncthreads();   // rows are cross-wave from here

  // ---- phase 2: lin1, wave computes 16 rows x cols [wave*32, wave*32+32) ----
  bf16x8 af[4];
  #pragma unroll
  for (int c = 0; c < 4; c++)
    af[c] = *(const bf16x8*)&hs[sub][c * 16 + grp * 4];

  f32x4 acc[2];
  #pragma unroll
  for (int t = 0; t < 2; t++) acc[t] = (f32x4){0.f, 0.f, 0.f, 0.f};
  #pragma unroll
  for (int c = 0; c < 4; c++) {
    #pragma unroll
    for (int t = 0; t < 2; t++) {
      size_t base = ((size_t)(c * 8 + wave * 2 + t) * 64 + lane) * 8;
      bf16x8 bh = *(const bf16x8*)(l1h + base);
      bf16x8 bl = *(const bf16x8*)(l1l + base);
      acc[t] = __builtin_amdgcn_mfma_f32_16x16x32_bf16(af[c], bh, acc[t], 0, 0, 0);
      acc[t] = __builtin_amdgcn_mfma_f32_16x16x32_bf16(af[c], bl, acc[t], 0, 0, 0);
    }
  }
  #pragma unroll
  for (int t = 0; t < 2; t++) {
    int col = wave * 32 + t * 16 + sub;
    float bb = b1[col];
    #pragma unroll
    for (int r = 0; r < 4; r++) {
      float x = acc[t][r] + bb;
      x = x > 0.f ? x : 0.01f * x;
      fs[grp * 4 + r][col] = x;
    }
  }
  __syncthreads();   // lin2 A-frags read cross-wave fs columns

  // ---- phase 3: lin2 (3-term split), wave computes 16 rows x cols [wave*16, +16) ----
  f32x4 acc2 = (f32x4){0.f, 0.f, 0.f, 0.f};
  #pragma unroll
  for (int c = 0; c < 4; c++) {
    bf16x8 ahi, alo;
    const float* lp = &fs[sub][c * 32 + grp * 8];
    float4 f0 = *(const float4*)lp;
    float4 f1 = *(const float4*)(lp + 4);
    float f[8] = {f0.x, f0.y, f0.z, f0.w, f1.x, f1.y, f1.z, f1.w};
    #pragma unroll
    for (int j = 0; j < 8; j++) {
      u16 h = f2bf_rne(f[j]);
      ahi[j] = (short)h;
      alo[j] = (short)f2bf_rne(f[j] - bf2f(h));
    }
    size_t base = ((size_t)(c * 4 + wave) * 64 + lane) * 8;
    bf16x8 bh = *(const bf16x8*)(l2h + base);
    bf16x8 bl = *(const bf16x8*)(l2l + base);
    acc2 = __builtin_amdgcn_mfma_f32_16x16x32_bf16(ahi, bh, acc2, 0, 0, 0);
    acc2 = __builtin_amdgcn_mfma_f32_16x16x32_bf16(alo, bh, acc2, 0, 0, 0);
    acc2 = __builtin_amdgcn_mfma_f32_16x16x32_bf16(ahi, bl, acc2, 0, 0, 0);
  }
  {
    float bb = b2[wave * 16 + sub];
    #pragma unroll
    for (int r = 0; r < 4; r++) {
      int grow = row0 + grp * 4 + r;
      if (grow < NN)
        out[(size_t)grow * 64 + wave * 16 + sub] = acc2[r] + bb;
    }
  }
}

// ---------------- launch ----------------

extern "C" void kernel_launch(void* const* d_in, const int* in_sizes, int n_in,
                              void* d_out, int out_size, void* d_ws, size_t ws_size,
                              hipStream_t stream) {
  const float* x       = (const float*)d_in[0];
  const int*   ei      = (const int*)  d_in[1];
  const float* ew      = (const float*)d_in[2];
  const float* w1      = (const float*)d_in[3];
  const float* b1      = (const float*)d_in[4];
  const float* bn1_g   = (const float*)d_in[5];
  const float* bn1_b   = (const float*)d_in[6];
  const float* bn1_m   = (const float*)d_in[7];
  const float* bn1_v   = (const float*)d_in[8];
  const float* conv_ws = (const float*)d_in[9];
  const float* conv_bs = (const float*)d_in[10];
  const float* bns_g   = (const float*)d_in[11];
  const float* bns_b   = (const float*)d_in[12];
  const float* bns_m   = (const float*)d_in[13];
  const float* bns_v   = (const float*)d_in[14];
  const float* lin1_w  = (const float*)d_in[15];
  const float* lin1_b  = (const float*)d_in[16];
  const float* lin2_w  = (const float*)d_in[17];
  const float* lin2_b  = (const float*)d_in[18];
  float* out = (float*)d_out;

  size_t off = 0;
  auto alloc = [&](size_t elems) -> void* {
    void* p = (char*)d_ws + off * 4;
    off += (elems + 3) & ~(size_t)3;
    return p;
  };
  unsigned* gcur = (unsigned*)alloc(NBUK * 16);
  u64*      bins = (u64*)     alloc((size_t)NBUK * RCAP * 2);
  unsigned* ell  = (unsigned*)alloc((size_t)NN * SLOTS);
  float*    dis  = (float*)   alloc(NN);
  float*    beff = (float*)   alloc(3 * CH);
  u16*      hwa  = (u16*)     alloc((size_t)NN * CH / 2);  // gather src A
  u16*      hwb  = (u16*)     alloc((size_t)NN * CH / 2);  // gather src B
  u16*      h1   = (u16*)     alloc((size_t)NN * CH / 2);  // residual 1
  u16*      h2   = (u16*)     alloc((size_t)NN * CH / 2);  // residual 2
  u16* w1h = (u16*)alloc(CH * CH / 2); u16* w1l = (u16*)alloc(CH * CH / 2);
  u16* c0h = (u16*)alloc(CH * CH / 2); u16* c0l = (u16*)alloc(CH * CH / 2);
  u16* c1h = (u16*)alloc(CH * CH / 2); u16* c1l = (u16*)alloc(CH * CH / 2);
  u16* l1h = (u16*)alloc(CH * CH / 2); u16* l1l = (u16*)alloc(CH * CH / 2);
  u16* l2h = (u16*)alloc(CH * 64 / 2); u16* l2l = (u16*)alloc(CH * 64 / 2);

  const int nb_fuse = (NN + 15) / 16;         // 3125
  dim3 B(256);

  hipMemsetAsync(gcur, 0, NBUK * 16 * sizeof(unsigned), stream);

  // bin (blocks 0..390) + weight swizzle (blocks 391..680)
  binw_kernel<<<NB_BIN + NB_WZ, B, 0, stream>>>(ei, ew, gcur, bins,
      w1, bn1_g, bn1_v, conv_ws, bns_g, bns_v, lin1_w, lin2_w,
      b1, bn1_b, bn1_m, conv_bs, bns_b, bns_m,
      w1h, w1l, c0h, c0l, c1h, c1l, l1h, l1l, l2h, l2l, beff);

  // scatter -> ELL + dis, then layer-1 GEMM for the same 64-node range
  scatgemm_kernel<<<NBUK, B, 0, stream>>>(gcur, bins, ell, dis, x, w1h, w1l, hwa);

  // agg1 + gemm2: h1 = lrelu(agg(hwa)+beff0); hwb = dis * (h1 @ W2')
  fuse_kernel<false><<<nb_fuse, B, 0, stream>>>(hwa, ell, dis, beff, nullptr,
      c0h, c0l, h1, hwb);

  // agg2 + gemm3: h2 = lrelu(agg(hwb)+beff1+h1); hwa = dis * (h2 @ W3')
  fuse_kernel<true><<<nb_fuse, B, 0, stream>>>(hwb, ell, dis, beff + CH, h1,
      c1h, c1l, h2, hwa);

  // agg3 + lin1 + lin2 -> out
  fuse_last_kernel<<<nb_fuse, B, 0, stream>>>(hwa, ell, dis, beff + 2 * CH, h2,
      l1h, l1l, lin1_b, l2h, l2l, lin2_b, out);
}

// Round 7
// 296.772 us; speedup vs baseline: 1.0788x; 1.0788x over previous
//
#include <hip/hip_runtime.h>
#include <hip/hip_bf16.h>

// GCN: h = lrelu(bn(gcn(x,W1)))  ; 2x h = lrelu(bn(gcn(h,Wi)) + h) ; lrelu(h@L1+b) ; h@L2+b
// R16: R14's proven fuse path (quarter-wave gather, traffic-clean: fuse_last 63us
// FETCH 127MB WRITE 12.5MB; per-group variant re-measured dirty twice and retired)
// + R15's dispatch merges (bin+wswz single kernel; scatter+gemm1 single kernel with
// dis through LDS). 5 dispatches + 1 memset. Numerics identical to R14.

constexpr int   NN    = 50000;
constexpr int   EE    = 800000;
constexpr int   CH    = 128;
constexpr int   SLOTS = 64;               // word0 = counter, slots 1..63 = edges
constexpr int   NBUK  = 782;              // buckets of 64 nodes (dst >> 6)
constexpr int   RCAP  = 2048;             // bin region capacity per bucket
constexpr int   EPB   = 2048;             // edges per bin block
constexpr int   NB_BIN = (EE + EPB - 1) / EPB;       // 391
constexpr int   NB_WZ  = (73728 + 384 + 255) / 256;  // 290
constexpr float EPS   = 1e-5f;

typedef __attribute__((ext_vector_type(8))) short bf16x8;
typedef __attribute__((ext_vector_type(4))) float f32x4;
typedef unsigned long long u64;
typedef unsigned short u16;

__device__ inline u16 f2bf_rne(float f) {
  unsigned u = __float_as_uint(f);
  unsigned r = u + 0x7fffu + ((u >> 16) & 1u);
  return (u16)(r >> 16);
}
__device__ inline float bf2f(unsigned h16) {          // low 16 bits -> float
  return __uint_as_float(h16 << 16);
}

// ---------------- pass 1: bin edges by dst bucket, + weight swizzle ----------------

__global__ __launch_bounds__(256) void binw_kernel(
    const int* __restrict__ ei, const float* __restrict__ ew,
    unsigned* __restrict__ gcur, u64* __restrict__ bins,
    const float* __restrict__ w1, const float* __restrict__ bn1_g, const float* __restrict__ bn1_v,
    const float* __restrict__ conv_ws, const float* __restrict__ bns_g, const float* __restrict__ bns_v,
    const float* __restrict__ lin1_w, const float* __restrict__ lin2_w,
    const float* __restrict__ b1, const float* __restrict__ bn1_b, const float* __restrict__ bn1_m,
    const float* __restrict__ conv_bs, const float* __restrict__ bns_b, const float* __restrict__ bns_m,
    u16* __restrict__ w1h, u16* __restrict__ w1l,
    u16* __restrict__ c0h, u16* __restrict__ c0l,
    u16* __restrict__ c1h, u16* __restrict__ c1l,
    u16* __restrict__ l1h, u16* __restrict__ l1l,
    u16* __restrict__ l2h, u16* __restrict__ l2l,
    float* __restrict__ beff)
{
  const int tid = threadIdx.x;
  if (blockIdx.x >= NB_BIN) {
    // ---- wswz role ----
    int idx = (blockIdx.x - NB_BIN) * 256 + tid;
    if (idx >= 73728) {
      int r = idx - 73728;
      if (r >= 384) return;
      int l = r >> 7, c = r & 127;
      float bc, gg, bb, mm, vv;
      if (l == 0) { bc = b1[c]; gg = bn1_g[c]; bb = bn1_b[c]; mm = bn1_m[c]; vv = bn1_v[c]; }
      else {
        int o = (l - 1) * 128 + c;
        bc = conv_bs[o]; gg = bns_g[o]; bb = bns_b[o]; mm = bns_m[o]; vv = bns_v[o];
      }
      beff[r] = (bc - mm) * gg * rsqrtf(vv + EPS) + bb;
      return;
    }
    const float* W; const float* g = nullptr; const float* v = nullptr;
    u16 *hi, *lo; int CO = 128; int local;
    if      (idx < 16384) { W = w1;              g = bn1_g;     v = bn1_v;     hi = w1h; lo = w1l; local = idx; }
    else if (idx < 32768) { W = conv_ws;         g = bns_g;     v = bns_v;     hi = c0h; lo = c0l; local = idx - 16384; }
    else if (idx < 49152) { W = conv_ws + 16384; g = bns_g+128; v = bns_v+128; hi = c1h; lo = c1l; local = idx - 32768; }
    else if (idx < 65536) { W = lin1_w;                                        hi = l1h; lo = l1l; local = idx - 49152; }
    else                  { W = lin2_w;                                        hi = l2h; lo = l2l; local = idx - 65536; CO = 64; }
    int k = local / CO, n = local % CO;
    float w = W[local];
    if (g) w *= g[n] * rsqrtf(v[n] + EPS);
    int NCT = CO / 16;
    int kchunk = k >> 5, kin = k & 31, quad = kin >> 3, j = kin & 7;
    int ct = n >> 4, l = (quad << 4) | (n & 15);
    size_t pos = ((size_t)(kchunk * NCT + ct) * 64 + l) * 8 + j;
    u16 h = f2bf_rne(w);
    hi[pos] = h;
    lo[pos] = f2bf_rne(w - bf2f(h));
    return;
  }
  // ---- bin role ----
  __shared__ unsigned cnt[NBUK];
  __shared__ unsigned base[NBUK];
  for (int b = tid; b < NBUK; b += 256) cnt[b] = 0;
  __syncthreads();
  const int e0 = blockIdx.x * EPB;
  unsigned pk[8]; u16 bkt[8]; u16 rnk[8]; unsigned char dl[8];
  #pragma unroll
  for (int i = 0; i < 8; i++) {
    int e = e0 + i * 256 + tid;
    if (e < EE) {
      int s = ei[e], d = ei[EE + e];
      float w = ew[e];
      bkt[i] = (u16)(d >> 6);
      dl[i]  = (unsigned char)(d & 63);
      pk[i]  = ((unsigned)f2bf_rne(w) << 16) | (unsigned)s;
      rnk[i] = (u16)atomicAdd(&cnt[bkt[i]], 1u);
    } else bkt[i] = 0xffffu;
  }
  __syncthreads();
  for (int b = tid; b < NBUK; b += 256) {
    unsigned c = cnt[b];
    base[b] = c ? atomicAdd(&gcur[b * 16], c) : 0u;
  }
  __syncthreads();
  #pragma unroll
  for (int i = 0; i < 8; i++) {
    if (bkt[i] == 0xffffu) continue;
    unsigned pos = base[bkt[i]] + rnk[i];
    if (pos < RCAP)
      bins[(size_t)bkt[i] * RCAP + pos] = ((u64)dl[i] << 32) | pk[i];
  }
}

// ---------------- pass 2: scatter bucket -> ELL, then layer-1 GEMM for same rows ----

__global__ __launch_bounds__(256) void scatgemm_kernel(
    const unsigned* __restrict__ gcur, const u64* __restrict__ bins,
    unsigned* __restrict__ ell, float* __restrict__ dis,
    const float* __restrict__ Ain,
    const u16* __restrict__ Whi, const u16* __restrict__ Wlo,
    u16* __restrict__ Cout)
{
  __shared__ unsigned rank[64];
  __shared__ float    wsum[64];
  __shared__ float    disl[64];
  __shared__ float    lds[64][CH + 4];
  const int b   = blockIdx.x;
  const int tid = threadIdx.x;

  // ---- phase A: scatter ----
  if (tid < 64) { rank[tid] = 1u; wsum[tid] = 0.f; }
  __syncthreads();
  unsigned cnt = gcur[b * 16];
  if (cnt > RCAP) cnt = RCAP;
  const u64* src = bins + (size_t)b * RCAP;
  for (unsigned i = tid; i < cnt; i += 256) {
    u64 v = src[i];
    unsigned pk = (unsigned)v;
    unsigned dl = (unsigned)(v >> 32);
    unsigned r = atomicAdd(&rank[dl], 1u);
    if (r < SLOTS)
      ell[((size_t)(b * 64 + dl)) * SLOTS + r] = pk;
    atomicAdd(&wsum[dl], bf2f(pk >> 16));
  }
  __syncthreads();
  if (tid < 64) {
    int node = b * 64 + tid;
    float d = rsqrtf(1.0f + wsum[tid]);
    disl[tid] = d;
    if (node < NN) {
      unsigned c = rank[tid];
      if (c > SLOTS) c = SLOTS;
      ell[(size_t)node * SLOTS] = c;
      dis[node] = d;
    }
  }
  __syncthreads();

  // ---- phase B: gemm1 for rows [b*64, b*64+64) ----
  const int wave = tid >> 6;
  const int lane = tid & 63;
  const int quad = lane >> 4;
  const int mrow = lane & 15;
  const int row0 = b * 64;

  int arow = row0 + wave * 16 + mrow;
  if (arow >= NN) arow = NN - 1;

  bf16x8 ahi[4], alo[4];
  const float* Ar = Ain + (size_t)arow * CH;
  #pragma unroll
  for (int c = 0; c < 4; c++) {
    int off = c * 32 + quad * 8;
    float4 f0 = *(const float4*)(Ar + off);
    float4 f1 = *(const float4*)(Ar + off + 4);
    float f[8] = {f0.x, f0.y, f0.z, f0.w, f1.x, f1.y, f1.z, f1.w};
    #pragma unroll
    for (int j = 0; j < 8; j++) {
      u16 h = f2bf_rne(f[j]);
      ahi[c][j] = (short)h;
      alo[c][j] = (short)f2bf_rne(f[j] - bf2f(h));
    }
  }

  f32x4 acc[8];
  #pragma unroll
  for (int t = 0; t < 8; t++) acc[t] = (f32x4){0.f, 0.f, 0.f, 0.f};
  #pragma unroll
  for (int c = 0; c < 4; c++) {
    #pragma unroll
    for (int t = 0; t < 8; t++) {
      size_t base = ((size_t)(c * 8 + t) * 64 + lane) * 8;
      bf16x8 bh = *(const bf16x8*)(Whi + base);
      bf16x8 bl = *(const bf16x8*)(Wlo + base);
      acc[t] = __builtin_amdgcn_mfma_f32_16x16x32_bf16(ahi[c], bh, acc[t], 0, 0, 0);
      acc[t] = __builtin_amdgcn_mfma_f32_16x16x32_bf16(alo[c], bh, acc[t], 0, 0, 0);
      acc[t] = __builtin_amdgcn_mfma_f32_16x16x32_bf16(ahi[c], bl, acc[t], 0, 0, 0);
    }
  }

  #pragma unroll
  for (int t = 0; t < 8; t++)
    #pragma unroll
    for (int r = 0; r < 4; r++)
      lds[wave * 16 + quad * 4 + r][t * 16 + mrow] = acc[t][r];
  __syncthreads();

  #pragma unroll
  for (int i = tid; i < 64 * CH / 4; i += 256) {
    int row = (i * 4) / CH;
    int col = (i * 4) % CH;
    int grow = row0 + row;
    if (grow >= NN) continue;
    float rs = disl[row];
    const float* lp = &lds[row][col];
    u16* cp = (u16*)Cout + (size_t)grow * CH + col;
    unsigned p0 = ((unsigned)f2bf_rne(lp[1] * rs) << 16) | f2bf_rne(lp[0] * rs);
    unsigned p1 = ((unsigned)f2bf_rne(lp[3] * rs) << 16) | f2bf_rne(lp[2] * rs);
    *(uint2*)cp = make_uint2(p0, p1);
  }
}

// ---------------- R10 quarter-wave gather (shared by fuse kernels) ----------------
// 4 nodes per wave, processed serially; per node, 16-edge chunks: 4 lane-groups each
// load one edge's row slice (16B/lane), FMA, then shfl_xor cross-group reduce.
// ell row for node r+1 prefetched one node ahead. Traffic-clean (127MB/12.5MB).
template<bool RES, bool WH>
__device__ __forceinline__ void gather4_qw(
    const u16* __restrict__ hwin, const unsigned* __restrict__ ell,
    const float* __restrict__ dis, const float* __restrict__ beff,
    const u16* __restrict__ res, u16* __restrict__ hout,
    unsigned* __restrict__ hsbase,           // &hs[wave*4][0], pitch 68 uints
    int nbase, int lane, int sub, int grp)
{
  int nd0 = nbase < NN ? nbase : NN - 1;
  unsigned wcur = ell[(size_t)nd0 * SLOTS + lane];
  for (int r = 0; r < 4; r++) {
    int node = nbase + r;
    int nd = node < NN ? node : NN - 1;
    unsigned myword = wcur;
    if (r < 3) {
      int n2 = node + 1 < NN ? node + 1 : NN - 1;
      wcur = ell[(size_t)n2 * SLOTS + lane];
    }
    int cnt = __shfl((int)myword, 0);
    if (cnt > SLOTS) cnt = SLOTS;
    float a[8] = {0.f, 0.f, 0.f, 0.f, 0.f, 0.f, 0.f, 0.f};
    for (int j = 0; j < cnt; j += 16) {
      unsigned sidx[4]; float wv[4];
      #pragma unroll
      for (int q = 0; q < 4; q++) {
        int jj = j + q * 4 + grp;
        unsigned e = (unsigned)__shfl((int)myword, jj & 63);
        float    w = (jj == 0) ? 1.0f : bf2f(e >> 16);
        unsigned s = (jj == 0) ? (unsigned)nd : (e & 0xffffu);
        if (jj >= cnt) { w = 0.f; s = (unsigned)nd; }
        sidx[q] = s; wv[q] = w;
      }
      uint4 h[4];
      #pragma unroll
      for (int q = 0; q < 4; q++)
        h[q] = *(const uint4*)(hwin + (size_t)sidx[q] * CH + sub * 8);
      #pragma unroll
      for (int q = 0; q < 4; q++) {
        float w = wv[q];
        a[0] = fmaf(w, bf2f(h[q].x & 0xffffu), a[0]); a[1] = fmaf(w, bf2f(h[q].x >> 16), a[1]);
        a[2] = fmaf(w, bf2f(h[q].y & 0xffffu), a[2]); a[3] = fmaf(w, bf2f(h[q].y >> 16), a[3]);
        a[4] = fmaf(w, bf2f(h[q].z & 0xffffu), a[4]); a[5] = fmaf(w, bf2f(h[q].z >> 16), a[5]);
        a[6] = fmaf(w, bf2f(h[q].w & 0xffffu), a[6]); a[7] = fmaf(w, bf2f(h[q].w >> 16), a[7]);
      }
    }
    #pragma unroll
    for (int k = 0; k < 8; k++) {
      a[k] += __shfl_xor(a[k], 16);
      a[k] += __shfl_xor(a[k], 32);
    }
    if (grp == 0) {
      float disd = dis[nd];
      int c = sub * 8;
      float4 be0 = *(const float4*)(beff + c);
      float4 be1 = *(const float4*)(beff + c + 4);
      float y[8];
      y[0] = a[0] * disd + be0.x; y[1] = a[1] * disd + be0.y;
      y[2] = a[2] * disd + be0.z; y[3] = a[3] * disd + be0.w;
      y[4] = a[4] * disd + be1.x; y[5] = a[5] * disd + be1.y;
      y[6] = a[6] * disd + be1.z; y[7] = a[7] * disd + be1.w;
      if constexpr (RES) {
        uint4 rr = *(const uint4*)(res + (size_t)nd * CH + c);
        y[0] += bf2f(rr.x & 0xffffu); y[1] += bf2f(rr.x >> 16);
        y[2] += bf2f(rr.y & 0xffffu); y[3] += bf2f(rr.y >> 16);
        y[4] += bf2f(rr.z & 0xffffu); y[5] += bf2f(rr.z >> 16);
        y[6] += bf2f(rr.w & 0xffffu); y[7] += bf2f(rr.w >> 16);
      }
      #pragma unroll
      for (int k = 0; k < 8; k++) y[k] = y[k] > 0.f ? y[k] : 0.01f * y[k];
      uint4 o;
      o.x = ((unsigned)f2bf_rne(y[1]) << 16) | f2bf_rne(y[0]);
      o.y = ((unsigned)f2bf_rne(y[3]) << 16) | f2bf_rne(y[2]);
      o.z = ((unsigned)f2bf_rne(y[5]) << 16) | f2bf_rne(y[4]);
      o.w = ((unsigned)f2bf_rne(y[7]) << 16) | f2bf_rne(y[6]);
      if constexpr (WH) {
        if (node < NN) *(uint4*)(hout + (size_t)node * CH + c) = o;
      }
      *(uint4*)&hsbase[r * 68 + sub * 4] = o;
    }
  }
}

// ---------------- fused agg + GEMM (layers 2/3), 16 nodes/block ----------------
// hwout epilogue goes through LDS so rows are written as full coalesced uint4 lines.
template<bool RES>
__global__ __launch_bounds__(256, 6) void fuse_kernel(
    const u16* __restrict__ hwin,
    const unsigned* __restrict__ ell, const float* __restrict__ dis,
    const float* __restrict__ beff, const u16* __restrict__ res,
    const u16* __restrict__ Whi, const u16* __restrict__ Wlo,
    u16* __restrict__ hout, u16* __restrict__ hwout)
{
  __shared__ unsigned hs[16][68];          // packed bf16 pairs, 2 ch per uint
  const int tid  = threadIdx.x;
  const int wave = tid >> 6;
  const int lane = tid & 63;
  const int sub  = lane & 15;
  const int grp  = lane >> 4;
  const int row0 = blockIdx.x * 16;

  gather4_qw<RES, true>(hwin, ell, dis, beff, res, hout,
                        &hs[wave * 4][0], row0 + wave * 4, lane, sub, grp);
  __syncthreads();   // rows are cross-wave in phase 2

  // ---- phase 2: GEMM, wave computes 16 rows x cols [wave*32, wave*32+32) ----
  bf16x8 af[4];
  #pragma unroll
  for (int c = 0; c < 4; c++)
    af[c] = *(const bf16x8*)&hs[sub][c * 16 + grp * 4];
  __syncthreads();   // all af reads complete before hs is overwritten below

  f32x4 acc[2];
  #pragma unroll
  for (int t = 0; t < 2; t++) acc[t] = (f32x4){0.f, 0.f, 0.f, 0.f};
  #pragma unroll
  for (int c = 0; c < 4; c++) {
    #pragma unroll
    for (int t = 0; t < 2; t++) {
      size_t base = ((size_t)(c * 8 + wave * 2 + t) * 64 + lane) * 8;
      bf16x8 bh = *(const bf16x8*)(Whi + base);
      bf16x8 bl = *(const bf16x8*)(Wlo + base);
      acc[t] = __builtin_amdgcn_mfma_f32_16x16x32_bf16(af[c], bh, acc[t], 0, 0, 0);
      acc[t] = __builtin_amdgcn_mfma_f32_16x16x32_bf16(af[c], bl, acc[t], 0, 0, 0);
    }
  }

  // scale + pack into LDS (u16 view, pitch 136), then coalesced uint4 row writes
  u16* hs16 = (u16*)&hs[0][0];
  #pragma unroll
  for (int r = 0; r < 4; r++) {
    int row = grp * 4 + r;                  // C/D: row = grp*4+r
    float rs = dis[row0 + row];
    #pragma unroll
    for (int t = 0; t < 2; t++)
      hs16[row * 136 + wave * 32 + t * 16 + sub] = f2bf_rne(acc[t][r] * rs);
  }
  __syncthreads();
  {
    int row   = tid >> 4;                   // 0..15
    int chunk = tid & 15;                   // 16B chunks
    uint4 o = *(const uint4*)(hs16 + row * 136 + chunk * 8);
    *(uint4*)(hwout + (size_t)(row0 + row) * CH + chunk * 8) = o;
  }
}

// ---------------- fused agg3 + lin1 + lin2: out = lrelu(h3@L1+b1)@L2+b2 ----------
__global__ __launch_bounds__(256, 6) void fuse_last_kernel(
    const u16* __restrict__ hwin,
    const unsigned* __restrict__ ell, const float* __restrict__ dis,
    const float* __restrict__ beff, const u16* __restrict__ res,
    const u16* __restrict__ l1h, const u16* __restrict__ l1l,
    const float* __restrict__ b1,
    const u16* __restrict__ l2h, const u16* __restrict__ l2l,
    const float* __restrict__ b2, float* __restrict__ out)
{
  __shared__ unsigned hs[16][68];          // bf16 h-tile
  __shared__ float    fs[16][132];         // fp32 lin1 output tile
  const int tid  = threadIdx.x;
  const int wave = tid >> 6;
  const int lane = tid & 63;
  const int sub  = lane & 15;
  const int grp  = lane >> 4;
  const int row0 = blockIdx.x * 16;

  gather4_qw<true, false>(hwin, ell, dis, beff, res, nullptr,
                          &hs[wave * 4][0], row0 + wave * 4, lane, sub, grp);
  __syncthreads();   // rows are cross-wave from here

  // ---- phase 2: lin1, wave computes 16 rows x cols [wave*32, wave*32+32) ----
  bf16x8 af[4];
  #pragma unroll
  for (int c = 0; c < 4; c++)
    af[c] = *(const bf16x8*)&hs[sub][c * 16 + grp * 4];

  f32x4 acc[2];
  #pragma unroll
  for (int t = 0; t < 2; t++) acc[t] = (f32x4){0.f, 0.f, 0.f, 0.f};
  #pragma unroll
  for (int c = 0; c < 4; c++) {
    #pragma unroll
    for (int t = 0; t < 2; t++) {
      size_t base = ((size_t)(c * 8 + wave * 2 + t) * 64 + lane) * 8;
      bf16x8 bh = *(const bf16x8*)(l1h + base);
      bf16x8 bl = *(const bf16x8*)(l1l + base);
      acc[t] = __builtin_amdgcn_mfma_f32_16x16x32_bf16(af[c], bh, acc[t], 0, 0, 0);
      acc[t] = __builtin_amdgcn_mfma_f32_16x16x32_bf16(af[c], bl, acc[t], 0, 0, 0);
    }
  }
  #pragma unroll
  for (int t = 0; t < 2; t++) {
    int col = wave * 32 + t * 16 + sub;
    float bb = b1[col];
    #pragma unroll
    for (int r = 0; r < 4; r++) {
      float x = acc[t][r] + bb;
      x = x > 0.f ? x : 0.01f * x;
      fs[grp * 4 + r][col] = x;
    }
  }
  __syncthreads();   // lin2 A-frags read cross-wave fs columns

  // ---- phase 3: lin2 (3-term split), wave computes 16 rows x cols [wave*16, +16) ----
  f32x4 acc2 = (f32x4){0.f, 0.f, 0.f, 0.f};
  #pragma unroll
  for (int c = 0; c < 4; c++) {
    bf16x8 ahi, alo;
    const float* lp = &fs[sub][c * 32 + grp * 8];
    float4 f0 = *(const float4*)lp;
    float4 f1 = *(const float4*)(lp + 4);
    float f[8] = {f0.x, f0.y, f0.z, f0.w, f1.x, f1.y, f1.z, f1.w};
    #pragma unroll
    for (int j = 0; j < 8; j++) {
      u16 h = f2bf_rne(f[j]);
      ahi[j] = (short)h;
      alo[j] = (short)f2bf_rne(f[j] - bf2f(h));
    }
    size_t base = ((size_t)(c * 4 + wave) * 64 + lane) * 8;
    bf16x8 bh = *(const bf16x8*)(l2h + base);
    bf16x8 bl = *(const bf16x8*)(l2l + base);
    acc2 = __builtin_amdgcn_mfma_f32_16x16x32_bf16(ahi, bh, acc2, 0, 0, 0);
    acc2 = __builtin_amdgcn_mfma_f32_16x16x32_bf16(alo, bh, acc2, 0, 0, 0);
    acc2 = __builtin_amdgcn_mfma_f32_16x16x32_bf16(ahi, bl, acc2, 0, 0, 0);
  }
  {
    float bb = b2[wave * 16 + sub];
    #pragma unroll
    for (int r = 0; r < 4; r++) {
      int grow = row0 + grp * 4 + r;
      if (grow < NN)
        out[(size_t)grow * 64 + wave * 16 + sub] = acc2[r] + bb;
    }
  }
}

// ---------------- launch ----------------

extern "C" void kernel_launch(void* const* d_in, const int* in_sizes, int n_in,
                              void* d_out, int out_size, void* d_ws, size_t ws_size,
                              hipStream_t stream) {
  const float* x       = (const float*)d_in[0];
  const int*   ei      = (const int*)  d_in[1];
  const float* ew      = (const float*)d_in[2];
  const float* w1      = (const float*)d_in[3];
  const float* b1      = (const float*)d_in[4];
  const float* bn1_g   = (const float*)d_in[5];
  const float* bn1_b   = (const float*)d_in[6];
  const float* bn1_m   = (const float*)d_in[7];
  const float* bn1_v   = (const float*)d_in[8];
  const float* conv_ws = (const float*)d_in[9];
  const float* conv_bs = (const float*)d_in[10];
  const float* bns_g   = (const float*)d_in[11];
  const float* bns_b   = (const float*)d_in[12];
  const float* bns_m   = (const float*)d_in[13];
  const float* bns_v   = (const float*)d_in[14];
  const float* lin1_w  = (const float*)d_in[15];
  const float* lin1_b  = (const float*)d_in[16];
  const float* lin2_w  = (const float*)d_in[17];
  const float* lin2_b  = (const float*)d_in[18];
  float* out = (float*)d_out;

  size_t off = 0;
  auto alloc = [&](size_t elems) -> void* {
    void* p = (char*)d_ws + off * 4;
    off += (elems + 3) & ~(size_t)3;
    return p;
  };
  unsigned* gcur = (unsigned*)alloc(NBUK * 16);
  u64*      bins = (u64*)     alloc((size_t)NBUK * RCAP * 2);
  unsigned* ell  = (unsigned*)alloc((size_t)NN * SLOTS);
  float*    dis  = (float*)   alloc(NN);
  float*    beff = (float*)   alloc(3 * CH);
  u16*      hwa  = (u16*)     alloc((size_t)NN * CH / 2);  // gather src A
  u16*      hwb  = (u16*)     alloc((size_t)NN * CH / 2);  // gather src B
  u16*      h1   = (u16*)     alloc((size_t)NN * CH / 2);  // residual 1
  u16*      h2   = (u16*)     alloc((size_t)NN * CH / 2);  // residual 2
  u16* w1h = (u16*)alloc(CH * CH / 2); u16* w1l = (u16*)alloc(CH * CH / 2);
  u16* c0h = (u16*)alloc(CH * CH / 2); u16* c0l = (u16*)alloc(CH * CH / 2);
  u16* c1h = (u16*)alloc(CH * CH / 2); u16* c1l = (u16*)alloc(CH * CH / 2);
  u16* l1h = (u16*)alloc(CH * CH / 2); u16* l1l = (u16*)alloc(CH * CH / 2);
  u16* l2h = (u16*)alloc(CH * 64 / 2); u16* l2l = (u16*)alloc(CH * 64 / 2);

  const int nb_fuse = (NN + 15) / 16;         // 3125
  dim3 B(256);

  hipMemsetAsync(gcur, 0, NBUK * 16 * sizeof(unsigned), stream);

  // bin (blocks 0..390) + weight swizzle (blocks 391..680)
  binw_kernel<<<NB_BIN + NB_WZ, B, 0, stream>>>(ei, ew, gcur, bins,
      w1, bn1_g, bn1_v, conv_ws, bns_g, bns_v, lin1_w, lin2_w,
      b1, bn1_b, bn1_m, conv_bs, bns_b, bns_m,
      w1h, w1l, c0h, c0l, c1h, c1l, l1h, l1l, l2h, l2l, beff);

  // scatter -> ELL + dis, then layer-1 GEMM for the same 64-node range
  scatgemm_kernel<<<NBUK, B, 0, stream>>>(gcur, bins, ell, dis, x, w1h, w1l, hwa);

  // agg1 + gemm2: h1 = lrelu(agg(hwa)+beff0); hwb = dis * (h1 @ W2')
  fuse_kernel<false><<<nb_fuse, B, 0, stream>>>(hwa, ell, dis, beff, nullptr,
      c0h, c0l, h1, hwb);

  // agg2 + gemm3: h2 = lrelu(agg(hwb)+beff1+h1); hwa = dis * (h2 @ W3')
  fuse_kernel<true><<<nb_fuse, B, 0, stream>>>(hwb, ell, dis, beff + CH, h1,
      c1h, c1l, h2, hwa);

  // agg3 + lin1 + lin2 -> out
  fuse_last_kernel<<<nb_fuse, B, 0, stream>>>(hwa, ell, dis, beff + 2 * CH, h2,
      l1h, l1l, lin1_b, l2h, l2l, lin2_b, out);
}